// Round 2
// baseline (65.845 us; speedup 1.0000x reference)
//
#include <hip/hip_runtime.h>
#include <stdint.h>

#define T_DIM 64
#define IN_DIM 4096
#define OUT_DIM 8192
#define NGROUPS 16
#define GS 256
#define SPLITK 8
#define KCHUNK (IN_DIM / SPLITK)        // 512
#define STEPS (KCHUNK / 32)             // 16 K-steps of 32
#define GPC (KCHUNK / GS)               // 2 quant groups per chunk

typedef __attribute__((ext_vector_type(4))) float f32x4;
typedef __attribute__((ext_vector_type(8))) __bf16 bf16x8;

__global__ void zero_kernel(float4* __restrict__ p, int n4) {
    int i = blockIdx.x * blockDim.x + threadIdx.x;
    if (i < n4) p[i] = make_float4(0.f, 0.f, 0.f, 0.f);
}

__global__ void cvt_kernel(const float* __restrict__ x, __bf16* __restrict__ xb, int n) {
    int i = (blockIdx.x * blockDim.x + threadIdx.x) * 8;
    if (i < n) {
        float4 f0 = *(const float4*)(x + i);
        float4 f1 = *(const float4*)(x + i + 4);
        bf16x8 o;
        o[0] = (__bf16)f0.x; o[1] = (__bf16)f0.y; o[2] = (__bf16)f0.z; o[3] = (__bf16)f0.w;
        o[4] = (__bf16)f1.x; o[5] = (__bf16)f1.y; o[6] = (__bf16)f1.z; o[7] = (__bf16)f1.w;
        *(bf16x8*)(xb + i) = o;
    }
}

// Each wave: 64(M) x 16(N) output strip over one K-chunk of 512.
// Block = 4 waves = 64 consecutive output columns. grid = (8192/64, SPLITK).
template<bool PRE>
__global__ __launch_bounds__(256, 4)
void qgemm(const float* __restrict__ x, const __bf16* __restrict__ xb,
           const int* __restrict__ qw, const float* __restrict__ qrange,
           const float* __restrict__ qmin, float* __restrict__ out)
{
    const int lane = threadIdx.x & 63;
    const int wv   = threadIdx.x >> 6;
    const int r    = lane & 15;      // fragment row/col index
    const int q4   = lane >> 4;      // 0..3 quad (k-slot)
    const int o    = blockIdx.x * 64 + wv * 16 + r;   // output column
    const int ks   = blockIdx.y;
    const int kbase = ks * KCHUNK;

    const int* __restrict__ qrow = qw + (size_t)o * IN_DIM + kbase + q4 * 8;
    const __bf16* __restrict__ xrow = xb + (size_t)r * IN_DIM + kbase + q4 * 8;
    const float* __restrict__ xrowf = x + (size_t)r * IN_DIM + kbase + q4 * 8;

    float scale[GPC], mn[GPC];
    #pragma unroll
    for (int g = 0; g < GPC; ++g) {
        scale[g] = qrange[o * NGROUPS + ks * GPC + g];
        mn[g]    = qmin[o * NGROUPS + ks * GPC + g];
    }

    f32x4 acc[4] = {{0,0,0,0},{0,0,0,0},{0,0,0,0},{0,0,0,0}};

    // register double-buffer: named A/B so all indices are compile-time
    int4 cA0, cA1, cB0, cB1;
    bf16x8 aA[4], aB[4];

    auto load = [&](int s, int4& c0, int4& c1, bf16x8* a) {
        const int k0 = s * 32;
        c0 = *(const int4*)(qrow + k0);
        c1 = *(const int4*)(qrow + k0 + 4);
        #pragma unroll
        for (int m = 0; m < 4; ++m) {
            if (PRE) {
                a[m] = *(const bf16x8*)(xrow + (size_t)(m * 16) * IN_DIM + k0);
            } else {
                const float* xp = xrowf + (size_t)(m * 16) * IN_DIM + k0;
                float4 f0 = *(const float4*)xp;
                float4 f1 = *(const float4*)(xp + 4);
                bf16x8 t;
                t[0] = (__bf16)f0.x; t[1] = (__bf16)f0.y; t[2] = (__bf16)f0.z; t[3] = (__bf16)f0.w;
                t[4] = (__bf16)f1.x; t[5] = (__bf16)f1.y; t[6] = (__bf16)f1.z; t[7] = (__bf16)f1.w;
                a[m] = t;
            }
        }
    };

    auto compute = [&](int s, const int4& c0, const int4& c1, const bf16x8* a) {
        const float sc = scale[s / (GS / 32)];   // s is compile-time after unroll
        const float mi = mn[s / (GS / 32)];
        bf16x8 b;
        b[0] = (__bf16)((float)c0.x * sc + mi); b[1] = (__bf16)((float)c0.y * sc + mi);
        b[2] = (__bf16)((float)c0.z * sc + mi); b[3] = (__bf16)((float)c0.w * sc + mi);
        b[4] = (__bf16)((float)c1.x * sc + mi); b[5] = (__bf16)((float)c1.y * sc + mi);
        b[6] = (__bf16)((float)c1.z * sc + mi); b[7] = (__bf16)((float)c1.w * sc + mi);
        acc[0] = __builtin_amdgcn_mfma_f32_16x16x32_bf16(a[0], b, acc[0], 0, 0, 0);
        acc[1] = __builtin_amdgcn_mfma_f32_16x16x32_bf16(a[1], b, acc[1], 0, 0, 0);
        acc[2] = __builtin_amdgcn_mfma_f32_16x16x32_bf16(a[2], b, acc[2], 0, 0, 0);
        acc[3] = __builtin_amdgcn_mfma_f32_16x16x32_bf16(a[3], b, acc[3], 0, 0, 0);
    };

    load(0, cA0, cA1, aA);
    #pragma unroll
    for (int s = 0; s < STEPS; s += 2) {
        if (s + 1 < STEPS) load(s + 1, cB0, cB1, aB);   // prefetch next while A in flight
        compute(s, cA0, cA1, aA);
        if (s + 2 < STEPS) load(s + 2, cA0, cA1, aA);
        if (s + 1 < STEPS) compute(s + 1, cB0, cB1, aB);
    }

    // D layout: col = lane&15 (= o), row = q4*4 + j, per m-tile of 16
    #pragma unroll
    for (int m = 0; m < 4; ++m) {
        #pragma unroll
        for (int j = 0; j < 4; ++j) {
            const int t = m * 16 + q4 * 4 + j;
            unsafeAtomicAdd(&out[(size_t)t * OUT_DIM + o], acc[m][j]);
        }
    }
}

extern "C" void kernel_launch(void* const* d_in, const int* in_sizes, int n_in,
                              void* d_out, int out_size, void* d_ws, size_t ws_size,
                              hipStream_t stream)
{
    const float* x      = (const float*)d_in[0];
    const int*   qw     = (const int*)d_in[1];
    const float* qrange = (const float*)d_in[2];
    const float* qmin   = (const float*)d_in[3];
    float* out = (float*)d_out;

    // zero output (split-K accumulates with atomics; harness poisons d_out)
    const int n4 = out_size / 4;
    zero_kernel<<<dim3((n4 + 255) / 256), dim3(256), 0, stream>>>((float4*)d_out, n4);

    const int nx = T_DIM * IN_DIM;                  // 262144
    const size_t xb_bytes = (size_t)nx * sizeof(unsigned short);
    if (ws_size >= xb_bytes) {
        __bf16* xbp = (__bf16*)d_ws;
        cvt_kernel<<<dim3(nx / 8 / 256), dim3(256), 0, stream>>>(x, xbp, nx);
        qgemm<true><<<dim3(OUT_DIM / 64, SPLITK), dim3(256), 0, stream>>>(x, xbp, qw, qrange, qmin, out);
    } else {
        qgemm<false><<<dim3(OUT_DIM / 64, SPLITK), dim3(256), 0, stream>>>(x, nullptr, qw, qrange, qmin, out);
    }
}

// Round 3
// 51.801 us; speedup vs baseline: 1.2711x; 1.2711x over previous
//
#include <hip/hip_runtime.h>
#include <stdint.h>

#define T_DIM 64
#define IN_DIM 4096
#define OUT_DIM 8192
#define NGROUPS 16
#define GS 256
#define SPLITK 4
#define KCHUNK (IN_DIM / SPLITK)    // 1024
#define BK 128                      // codes staged per stage (512B per row)
#define NSTAGES (KCHUNK / BK)       // 8
#define GPC (KCHUNK / GS)           // 4 quant groups per K-chunk

typedef __attribute__((ext_vector_type(4))) float f32x4;
typedef __attribute__((ext_vector_type(8))) __bf16 bf16x8;

__global__ void zero_kernel(float4* __restrict__ p, int n4) {
    int i = blockIdx.x * blockDim.x + threadIdx.x;
    if (i < n4) p[i] = make_float4(0.f, 0.f, 0.f, 0.f);
}

__global__ void cvt_kernel(const float* __restrict__ x, __bf16* __restrict__ xb, int n) {
    int i = (blockIdx.x * blockDim.x + threadIdx.x) * 8;
    if (i < n) {
        float4 f0 = *(const float4*)(x + i);
        float4 f1 = *(const float4*)(x + i + 4);
        bf16x8 o;
        o[0] = (__bf16)f0.x; o[1] = (__bf16)f0.y; o[2] = (__bf16)f0.z; o[3] = (__bf16)f0.w;
        o[4] = (__bf16)f1.x; o[5] = (__bf16)f1.y; o[6] = (__bf16)f1.z; o[7] = (__bf16)f1.w;
        *(bf16x8*)(xb + i) = o;
    }
}

__device__ __forceinline__ void gld_lds16(const int* g, int* l) {
    __builtin_amdgcn_global_load_lds(
        (const __attribute__((address_space(1))) void*)g,
        (__attribute__((address_space(3))) void*)l, 16, 0, 0);
}

// Block = 4 waves, 256 threads; block owns 64 output columns x full M=64,
// over one K-chunk of 1024. Each wave owns 16 columns (rows of qweight) and
// stages ONLY its own rows into a private LDS slice -> no barriers needed.
// grid = (8192/64, SPLITK) = (128, 4) = 512 blocks = 2 resident per CU.
template<bool PRE>
__global__ __launch_bounds__(256, 2)
void qgemm(const float* __restrict__ x, const __bf16* __restrict__ xb,
           const int* __restrict__ qw, const float* __restrict__ qrange,
           const float* __restrict__ qmin, float* __restrict__ out)
{
    __shared__ int lds[2][64 * BK];   // 2 x 32KB double buffer

    const int lane  = threadIdx.x & 63;
    const int wv    = threadIdx.x >> 6;
    const int r     = lane & 15;      // fragment row/col index
    const int q4    = lane >> 4;      // k-slot (0..3)
    const int obase = blockIdx.x * 64;
    const int o     = obase + wv * 16 + r;   // this lane's output column
    const int ks    = blockIdx.y;
    const int kbase = ks * KCHUNK;

    const int jrow = lane >> 5;       // 0/1: which row of the pair this lane stages
    const int j5   = lane & 31;       // 16B-chunk index within the row (512B)
    const int rowloc0 = wv * 16;      // wave's private row range in the LDS tile

    float sc[GPC], mi[GPC];
    #pragma unroll
    for (int g = 0; g < GPC; ++g) {
        sc[g] = qrange[o * NGROUPS + ks * GPC + g];
        mi[g] = qmin[o * NGROUPS + ks * GPC + g];
    }

    const __bf16* xrow  = xb + (size_t)r * IN_DIM + kbase + q4 * 8;
    const float*  xrowf = x  + (size_t)r * IN_DIM + kbase + q4 * 8;

    f32x4 acc[4] = {{0,0,0,0},{0,0,0,0},{0,0,0,0},{0,0,0,0}};

    // ---- staging: issue 8 global_load_lds (each: 2 rows x 512B contiguous).
    // LDS dest is linear; the XOR swizzle is applied on the SOURCE address
    // (lane j5 fetches global 16B-chunk j5 ^ (row&7)) and again on the read.
    auto stage = [&](int s, int b) {
        #pragma unroll
        for (int i = 0; i < 8; ++i) {
            const int row  = rowloc0 + i * 2 + jrow;
            const int srck = 4 * (j5 ^ (row & 7));   // swizzled source k (ints)
            const int* gp  = qw + (size_t)(obase + row) * IN_DIM + kbase + s * BK + srck;
            gld_lds16(gp, &lds[b][(rowloc0 + i * 2) * BK]);
        }
    };

    auto compute = [&](int s, int b) {
        const float s0 = sc[s >> 1];   // BK=128, GS=256: group = s/2 (const after unroll)
        const float m0 = mi[s >> 1];
        const int rowl = rowloc0 + r;
        const int swz  = (r & 7) * 4;  // swizzle in int units (== <<4 in bytes)
        #pragma unroll
        for (int kk = 0; kk < BK / 32; ++kk) {
            const int kl = kk * 32 + q4 * 8;
            int4 c0 = *(const int4*)&lds[b][rowl * BK + ((kl) ^ swz)];
            int4 c1 = *(const int4*)&lds[b][rowl * BK + ((kl + 4) ^ swz)];
            bf16x8 bfr;
            bfr[0] = (__bf16)((float)c0.x * s0 + m0);
            bfr[1] = (__bf16)((float)c0.y * s0 + m0);
            bfr[2] = (__bf16)((float)c0.z * s0 + m0);
            bfr[3] = (__bf16)((float)c0.w * s0 + m0);
            bfr[4] = (__bf16)((float)c1.x * s0 + m0);
            bfr[5] = (__bf16)((float)c1.y * s0 + m0);
            bfr[6] = (__bf16)((float)c1.z * s0 + m0);
            bfr[7] = (__bf16)((float)c1.w * s0 + m0);
            const int koff = s * BK + kk * 32;
            bf16x8 a[4];
            #pragma unroll
            for (int m = 0; m < 4; ++m) {
                if (PRE) {
                    a[m] = *(const bf16x8*)(xrow + (size_t)(m * 16) * IN_DIM + koff);
                } else {
                    const float* xp = xrowf + (size_t)(m * 16) * IN_DIM + koff;
                    float4 f0 = *(const float4*)xp;
                    float4 f1 = *(const float4*)(xp + 4);
                    bf16x8 t;
                    t[0] = (__bf16)f0.x; t[1] = (__bf16)f0.y; t[2] = (__bf16)f0.z; t[3] = (__bf16)f0.w;
                    t[4] = (__bf16)f1.x; t[5] = (__bf16)f1.y; t[6] = (__bf16)f1.z; t[7] = (__bf16)f1.w;
                    a[m] = t;
                }
            }
            acc[0] = __builtin_amdgcn_mfma_f32_16x16x32_bf16(a[0], bfr, acc[0], 0, 0, 0);
            acc[1] = __builtin_amdgcn_mfma_f32_16x16x32_bf16(a[1], bfr, acc[1], 0, 0, 0);
            acc[2] = __builtin_amdgcn_mfma_f32_16x16x32_bf16(a[2], bfr, acc[2], 0, 0, 0);
            acc[3] = __builtin_amdgcn_mfma_f32_16x16x32_bf16(a[3], bfr, acc[3], 0, 0, 0);
        }
    };

    stage(0, 0);
    #pragma unroll
    for (int s = 0; s < NSTAGES; ++s) {
        if (s + 1 < NSTAGES) {
            stage(s + 1, (s + 1) & 1);
            // counted wait: allow the 8 just-issued prefetch loads to stay in
            // flight; guarantees stage(s) has landed (vmcnt is in-order).
            asm volatile("s_waitcnt vmcnt(8)" ::: "memory");
        } else {
            asm volatile("s_waitcnt vmcnt(0)" ::: "memory");
        }
        __builtin_amdgcn_sched_barrier(0);
        compute(s, s & 1);
    }

    // D layout: col = lane&15 (= o), row = q4*4 + j, per m-tile of 16
    #pragma unroll
    for (int m = 0; m < 4; ++m) {
        #pragma unroll
        for (int j = 0; j < 4; ++j) {
            const int t = m * 16 + q4 * 4 + j;
            unsafeAtomicAdd(&out[(size_t)t * OUT_DIM + o], acc[m][j]);
        }
    }
}

extern "C" void kernel_launch(void* const* d_in, const int* in_sizes, int n_in,
                              void* d_out, int out_size, void* d_ws, size_t ws_size,
                              hipStream_t stream)
{
    const float* x      = (const float*)d_in[0];
    const int*   qw     = (const int*)d_in[1];
    const float* qrange = (const float*)d_in[2];
    const float* qmin   = (const float*)d_in[3];
    float* out = (float*)d_out;

    // zero output (split-K accumulates with atomics; harness poisons d_out)
    const int n4 = out_size / 4;
    zero_kernel<<<dim3((n4 + 255) / 256), dim3(256), 0, stream>>>((float4*)d_out, n4);

    const int nx = T_DIM * IN_DIM;                  // 262144
    const size_t xb_bytes = (size_t)nx * sizeof(unsigned short);
    if (ws_size >= xb_bytes) {
        __bf16* xbp = (__bf16*)d_ws;
        cvt_kernel<<<dim3(nx / 8 / 256), dim3(256), 0, stream>>>(x, xbp, nx);
        qgemm<true><<<dim3(OUT_DIM / 64, SPLITK), dim3(256), 0, stream>>>(x, xbp, qw, qrange, qmin, out);
    } else {
        qgemm<false><<<dim3(OUT_DIM / 64, SPLITK), dim3(256), 0, stream>>>(x, nullptr, qw, qrange, qmin, out);
    }
}

// Round 4
// 49.724 us; speedup vs baseline: 1.3242x; 1.0418x over previous
//
#include <hip/hip_runtime.h>
#include <stdint.h>

#define T_DIM 64
#define IN_DIM 4096
#define OUT_DIM 8192
#define NGROUPS 16
#define GS 256
#define SPLITK 4
#define KCHUNK (IN_DIM / SPLITK)    // 1024
#define BK 128                      // codes staged per stage (512B per row)
#define NSTAGES (KCHUNK / BK)       // 8
#define GPC (KCHUNK / GS)           // 4 quant groups per K-chunk

typedef __attribute__((ext_vector_type(4))) float f32x4;
typedef __attribute__((ext_vector_type(8))) __bf16 bf16x8;

__global__ void zero_kernel(float4* __restrict__ p, int n4) {
    int i = blockIdx.x * blockDim.x + threadIdx.x;
    if (i < n4) p[i] = make_float4(0.f, 0.f, 0.f, 0.f);
}

__global__ void cvt_kernel(const float* __restrict__ x, __bf16* __restrict__ xb, int n) {
    int i = (blockIdx.x * blockDim.x + threadIdx.x) * 8;
    if (i < n) {
        float4 f0 = *(const float4*)(x + i);
        float4 f1 = *(const float4*)(x + i + 4);
        bf16x8 o;
        o[0] = (__bf16)f0.x; o[1] = (__bf16)f0.y; o[2] = (__bf16)f0.z; o[3] = (__bf16)f0.w;
        o[4] = (__bf16)f1.x; o[5] = (__bf16)f1.y; o[6] = (__bf16)f1.z; o[7] = (__bf16)f1.w;
        *(bf16x8*)(xb + i) = o;
    }
}

__device__ __forceinline__ void gld_lds16(const int* g, int* l) {
    __builtin_amdgcn_global_load_lds(
        (const __attribute__((address_space(1))) void*)g,
        (__attribute__((address_space(3))) void*)l, 16, 0, 0);
}

// Block = 4 waves, 256 threads; block owns 64 output columns x full M=64,
// over one K-chunk of 1024. Each wave owns 16 weight rows and stages ONLY its
// own rows into a private LDS slice -> no barriers. Per iteration, ONE load
// group [8 gld_lds + 16 x-frag loads] is issued, then a single counted
// s_waitcnt vmcnt(24) releases compute(s) while group(s+1) stays in flight.
// compute() touches no global memory -> no compiler-inserted drains.
// grid = (8192/64, SPLITK) = 512 blocks = 2 resident per CU (64KB LDS each).
template<bool PRE>
__global__ __launch_bounds__(256, 2)
void qgemm(const float* __restrict__ x, const __bf16* __restrict__ xb,
           const int* __restrict__ qw, const float* __restrict__ qrange,
           const float* __restrict__ qmin, float* __restrict__ out)
{
    __shared__ int lds[2][64 * BK];   // 2 x 32KB double buffer

    const int lane  = threadIdx.x & 63;
    const int wv    = threadIdx.x >> 6;
    const int r     = lane & 15;      // fragment row/col index
    const int q4    = lane >> 4;      // k-slot (0..3)
    const int obase = blockIdx.x * 64;
    const int o     = obase + wv * 16 + r;   // this lane's output column
    const int ks    = blockIdx.y;
    const int kbase = ks * KCHUNK;

    const int jrow = lane >> 5;       // 0/1: which row of the pair this lane stages
    const int j5   = lane & 31;       // 16B-chunk index within the row (512B)
    const int rowloc0 = wv * 16;      // wave's private row range in the LDS tile

    float sc[GPC], mi[GPC];
    #pragma unroll
    for (int g = 0; g < GPC; ++g) {
        sc[g] = qrange[o * NGROUPS + ks * GPC + g];
        mi[g] = qmin[o * NGROUPS + ks * GPC + g];
    }

    const __bf16* xrow  = xb + (size_t)r * IN_DIM + kbase + q4 * 8;
    const float*  xrowf = x  + (size_t)r * IN_DIM + kbase + q4 * 8;

    f32x4 acc[4] = {{0,0,0,0},{0,0,0,0},{0,0,0,0},{0,0,0,0}};

    // x-fragment register double buffer: [buf][m*4+kk]; all indices are
    // compile-time after full unroll (rule #20).
    bf16x8 xf[2][16];

    // ---- weight staging: 8 global_load_lds (each: 2 rows x 512B contiguous).
    // LDS dest linear; XOR swizzle applied on SOURCE addr and again on read.
    auto stage = [&](int s, int b) {
        #pragma unroll
        for (int i = 0; i < 8; ++i) {
            const int row  = rowloc0 + i * 2 + jrow;
            const int srck = 4 * (j5 ^ (row & 7));   // swizzled source k (ints)
            const int* gp  = qw + (size_t)(obase + row) * IN_DIM + kbase + s * BK + srck;
            gld_lds16(gp, &lds[b][(rowloc0 + i * 2) * BK]);
        }
    };

    auto xload = [&](int s, int buf) {
        #pragma unroll
        for (int m = 0; m < 4; ++m) {
            #pragma unroll
            for (int kk = 0; kk < 4; ++kk) {
                const int koff = s * BK + kk * 32;
                if (PRE) {
                    xf[buf][m * 4 + kk] =
                        *(const bf16x8*)(xrow + (size_t)(m * 16) * IN_DIM + koff);
                } else {
                    const float* xp = xrowf + (size_t)(m * 16) * IN_DIM + koff;
                    float4 f0 = *(const float4*)xp;
                    float4 f1 = *(const float4*)(xp + 4);
                    bf16x8 t;
                    t[0] = (__bf16)f0.x; t[1] = (__bf16)f0.y; t[2] = (__bf16)f0.z; t[3] = (__bf16)f0.w;
                    t[4] = (__bf16)f1.x; t[5] = (__bf16)f1.y; t[6] = (__bf16)f1.z; t[7] = (__bf16)f1.w;
                    xf[buf][m * 4 + kk] = t;
                }
            }
        }
    };

    auto compute = [&](int s, int b, int xbuf) {
        const float s0 = sc[s >> 1];   // BK=128, GS=256: group = s/2 (const after unroll)
        const float m0 = mi[s >> 1];
        const int rowl = rowloc0 + r;
        const int swz  = (r & 7) * 4;  // swizzle in int units (== <<4 in bytes)
        #pragma unroll
        for (int kk = 0; kk < BK / 32; ++kk) {
            const int kl = kk * 32 + q4 * 8;
            int4 c0 = *(const int4*)&lds[b][rowl * BK + ((kl) ^ swz)];
            int4 c1 = *(const int4*)&lds[b][rowl * BK + ((kl + 4) ^ swz)];
            bf16x8 bfr;
            bfr[0] = (__bf16)((float)c0.x * s0 + m0);
            bfr[1] = (__bf16)((float)c0.y * s0 + m0);
            bfr[2] = (__bf16)((float)c0.z * s0 + m0);
            bfr[3] = (__bf16)((float)c0.w * s0 + m0);
            bfr[4] = (__bf16)((float)c1.x * s0 + m0);
            bfr[5] = (__bf16)((float)c1.y * s0 + m0);
            bfr[6] = (__bf16)((float)c1.z * s0 + m0);
            bfr[7] = (__bf16)((float)c1.w * s0 + m0);
            acc[0] = __builtin_amdgcn_mfma_f32_16x16x32_bf16(xf[xbuf][0 * 4 + kk], bfr, acc[0], 0, 0, 0);
            acc[1] = __builtin_amdgcn_mfma_f32_16x16x32_bf16(xf[xbuf][1 * 4 + kk], bfr, acc[1], 0, 0, 0);
            acc[2] = __builtin_amdgcn_mfma_f32_16x16x32_bf16(xf[xbuf][2 * 4 + kk], bfr, acc[2], 0, 0, 0);
            acc[3] = __builtin_amdgcn_mfma_f32_16x16x32_bf16(xf[xbuf][3 * 4 + kk], bfr, acc[3], 0, 0, 0);
        }
    };

    // prologue: group(0) in flight
    stage(0, 0);
    xload(0, 0);
    #pragma unroll
    for (int s = 0; s < NSTAGES; ++s) {
        if (s + 1 < NSTAGES) {
            stage(s + 1, (s + 1) & 1);     // group(s+1): 8 gld_lds ...
            xload(s + 1, (s + 1) & 1);     //   ... + 16 x loads = 24 vmem ops
            // wait until <=24 outstanding: group(s) (weights AND x) has landed,
            // group(s+1) stays in flight across compute(s).
            asm volatile("s_waitcnt vmcnt(24)" ::: "memory");
        } else {
            asm volatile("s_waitcnt vmcnt(0)" ::: "memory");
        }
        __builtin_amdgcn_sched_barrier(0);
        compute(s, s & 1, s & 1);
    }

    // D layout: col = lane&15 (= o), row = q4*4 + j, per m-tile of 16
    #pragma unroll
    for (int m = 0; m < 4; ++m) {
        #pragma unroll
        for (int j = 0; j < 4; ++j) {
            const int t = m * 16 + q4 * 4 + j;
            unsafeAtomicAdd(&out[(size_t)t * OUT_DIM + o], acc[m][j]);
        }
    }
}

extern "C" void kernel_launch(void* const* d_in, const int* in_sizes, int n_in,
                              void* d_out, int out_size, void* d_ws, size_t ws_size,
                              hipStream_t stream)
{
    const float* x      = (const float*)d_in[0];
    const int*   qw     = (const int*)d_in[1];
    const float* qrange = (const float*)d_in[2];
    const float* qmin   = (const float*)d_in[3];
    float* out = (float*)d_out;

    // zero output (split-K accumulates with atomics; harness poisons d_out)
    const int n4 = out_size / 4;
    zero_kernel<<<dim3((n4 + 255) / 256), dim3(256), 0, stream>>>((float4*)d_out, n4);

    const int nx = T_DIM * IN_DIM;                  // 262144
    const size_t xb_bytes = (size_t)nx * sizeof(unsigned short);
    if (ws_size >= xb_bytes) {
        __bf16* xbp = (__bf16*)d_ws;
        cvt_kernel<<<dim3(nx / 8 / 256), dim3(256), 0, stream>>>(x, xbp, nx);
        qgemm<true><<<dim3(OUT_DIM / 64, SPLITK), dim3(256), 0, stream>>>(x, xbp, qw, qrange, qmin, out);
    } else {
        qgemm<false><<<dim3(OUT_DIM / 64, SPLITK), dim3(256), 0, stream>>>(x, nullptr, qw, qrange, qmin, out);
    }
}